// Round 8
// baseline (4368.788 us; speedup 1.0000x reference)
//
#include <hip/hip_runtime.h>
#include <cstdint>

typedef unsigned short u16;
typedef __attribute__((ext_vector_type(8))) short short8;
typedef __attribute__((ext_vector_type(4))) float f32x4;

#define B_ 16
#define P_ 128
#define T_ 16384
#define H_ 256
#define O_ 32
#define MBLK 16
#define NBLOCKS 128
#define NTHREADS 512

// workspace layout (bytes)
#define WS_STARTS 0         // 2048 * int32
#define WS_B0     8192      // 1024 fp32
#define WS_B1     12288     // 1024 fp32
#define WS_STREAM 16384     // 8 waves * 27 phases * 4096 u16 * 2B = 1769472 B

#define HOFF 8388608LL      // h_t offset in out (floats)
#define COFF 9437184LL      // c_t offset

#define SBAR0 __builtin_amdgcn_sched_barrier(0)
#define LGKM0 asm volatile("s_waitcnt lgkmcnt(0)" ::: "memory")
#define BLOCK_BARRIER() do { SBAR0; LGKM0; __builtin_amdgcn_s_barrier(); SBAR0; } while (0)

// counted vmcnt gate: memory clobber + sched_barrier(0) pins consumers below
#define WAITV(NSTR) do { \
  asm volatile("s_waitcnt vmcnt(" NSTR ")" ::: "memory"); SBAR0; } while (0)

// weight fragment load: straight to VGPRs, invisible to compiler's vmcnt tracking.
// nt = non-temporal (no L1 allocation): weights stream with zero per-CU reuse;
// R5 profile points at L1 line-fill throughput as the ~32 B/cy/CU wall.
#define GL(dst, vo, IMMSTR) \
  asm volatile("global_load_dwordx4 %0, %1, %2 offset:" IMMSTR " nt" \
               : "=v"(dst) : "v"(vo), "s"(wbv))
#define LOADPH(bq, voff) do { \
  uint32_t vo_ = (voff); uint32_t vo2_ = vo_ + 4096u; \
  GL(bq[0], vo_,  "0");    GL(bq[1], vo_,  "1024"); \
  GL(bq[2], vo_,  "2048"); GL(bq[3], vo_,  "3072"); \
  GL(bq[4], vo2_, "0");    GL(bq[5], vo2_, "1024"); \
  GL(bq[6], vo2_, "2048"); GL(bq[7], vo2_, "3072"); } while (0)

#define GLX(dst, vo, IMMSTR) \
  asm volatile("global_load_dwordx4 %0, %1, %2 offset:" IMMSTR \
               : "=v"(dst) : "v"(vo), "s"(xbv))

// output store: inline asm so the compiler never emits its own vmcnt waits
#define GSTORE(ptr, val) \
  asm volatile("global_store_dword %0, %1, off" :: "v"(ptr), "v"(val))

__device__ __forceinline__ u16 f2bf(float f) {
  uint32_t u = __float_as_uint(f);
  u += 0x7FFFu + ((u >> 16) & 1u);
  return (u16)(u >> 16);
}
__device__ __forceinline__ float sigm(float x) { return 1.f / (1.f + __expf(-x)); }
__device__ __forceinline__ float tanhf_(float x) {
  float e = __expf(-2.f * fabsf(x));
  float t = (1.f - e) / (1.f + e);
  return x < 0.f ? -t : t;
}

__global__ void k_starts(const int* __restrict__ lpp, int* __restrict__ starts) {
  int b = threadIdx.x;
  if (b >= B_) return;
  int run = 0;
  for (int p = 0; p < P_; p++) { starts[b * P_ + p] = run; run += lpp[b * P_ + p]; }
}

// Pack all weights into one contiguous per-wave phase stream:
// idx = ((wv*27 + p)*8 + f)*512 + lane*8 + i     (f = k-fragment index kf)
// phases: 0-1 wih0, 2-9 whh0, 10-17 wih1, 18-25 whh1, 26 wfc
__global__ void k_pack_stream(const float* __restrict__ Wih0, const float* __restrict__ Whh0,
                              const float* __restrict__ Wih1, const float* __restrict__ Whh1,
                              const float* __restrict__ Wfc, u16* __restrict__ o) {
  int idx = blockIdx.x * 256 + threadIdx.x;
  if (idx >= 8 * 27 * 4096) return;
  int i = idx & 7;
  int lane = (idx >> 3) & 63;
  int f = (idx >> 9) & 7;
  int pp = idx >> 12;
  int p = pp % 27, wv = pp / 27;
  int c = lane & 15, kg = lane >> 4, k = kg * 8 + i;
  float val;
  if (p < 2)        { int nt = p * 4 + (f >> 1), kf = f & 1;
                      int row = (nt & 3) * 256 + wv * 32 + ((nt >> 2) << 4) + c;
                      val = Wih0[row * 64 + kf * 32 + k]; }
  else if (p < 10)  { int nt = p - 2;
                      int row = (nt & 3) * 256 + wv * 32 + ((nt >> 2) << 4) + c;
                      val = Whh0[row * 256 + f * 32 + k]; }
  else if (p < 18)  { int nt = p - 10;
                      int row = (nt & 3) * 256 + wv * 32 + ((nt >> 2) << 4) + c;
                      val = Wih1[row * 256 + f * 32 + k]; }
  else if (p < 26)  { int nt = p - 18;
                      int row = (nt & 3) * 256 + wv * 32 + ((nt >> 2) << 4) + c;
                      val = Whh1[row * 256 + f * 32 + k]; }
  else              { int tile = wv & 1; int row = tile * 16 + c;
                      val = Wfc[row * 256 + f * 32 + k]; }
  o[idx] = f2bf(val);
}

__global__ void k_bias(const float* bih0, const float* bhh0,
                       const float* bih1, const float* bhh1,
                       float* b0, float* b1) {
  int n = blockIdx.x * 256 + threadIdx.x;
  if (n >= 1024) return;
  int wv = n >> 7, r = n & 127, nt = r >> 4, c = n & 15;
  int row = (nt & 3) * 256 + wv * 32 + ((nt >> 2) << 4) + c;
  b0[n] = bih0[row] + bhh0[row];
  b1[n] = bih1[row] + bhh1[row];
}

__launch_bounds__(NTHREADS, 1)
__global__ void lstm_main(const float* __restrict__ x,
                          const int* __restrict__ lpp,
                          const float* __restrict__ bfc,
                          const uint8_t* __restrict__ ws,
                          float* __restrict__ out) {
  const int g = blockIdx.x;
  const int tid = threadIdx.x;
  const int w = tid >> 6;
  const int lane = tid & 63;
  const int lr = lane & 15;
  const int lg = lane >> 4;

  __shared__ __align__(16) u16 h0p[16][264];
  __shared__ __align__(16) u16 h1p[16][264];
  __shared__ int len_s[16];
  __shared__ int start_s[16];
  __shared__ int bb_s[16];

  const int* starts = (const int*)(ws + WS_STARTS);
  if (tid < 16) {
    int sg = g * MBLK + tid;
    len_s[tid] = lpp[sg];
    start_s[tid] = starts[sg];
    bb_s[tid] = sg >> 7;
  }
  for (int i = tid; i < 16 * 264; i += NTHREADS) {
    ((u16*)h0p)[i] = 0;
    ((u16*)h1p)[i] = 0;
  }
  __syncthreads();   // prologue only — nothing in flight yet

  int maxlen = 0;
  #pragma unroll
  for (int i = 0; i < 16; i++) maxlen = max(maxlen, len_s[i]);

  int len_r[4];
  long long obase[4];
  #pragma unroll
  for (int v = 0; v < 4; v++) {
    int r = lg * 4 + v;
    len_r[v] = len_s[r];
    obase[v] = ((long long)bb_s[r] * T_ + start_s[r]) * O_ + (w & 1) * 16 + lr;
  }

  const float* b0p = (const float*)(ws + WS_B0);
  const float* b1p = (const float*)(ws + WS_B1);
  float b0r[8], b1r[8];
  #pragma unroll
  for (int nt = 0; nt < 8; nt++) {
    b0r[nt] = b0p[w * 128 + nt * 16 + lr];
    b1r[nt] = b1p[w * 128 + nt * 16 + lr];
  }
  float bfc_r = (w < 2) ? bfc[w * 16 + lr] : 0.f;

  const unsigned long long wbv = (unsigned long long)(ws + WS_STREAM);
  const unsigned long long xbv = (unsigned long long)x;
  const uint32_t lane_voff = ((uint32_t)w * 27u * 4096u + (uint32_t)lane * 8u) * 2u;
  const int lenrow = len_s[lr];
  const uint32_t xvbase =
      ((uint32_t)bb_s[lr] * (uint32_t)T_ + (uint32_t)start_s[lr]) * 256u + (uint32_t)lg * 32u;

  float h0r[8], c0r[8], h1r[8], c1r[8];
  #pragma unroll
  for (int i = 0; i < 8; i++) { h0r[i] = 0.f; c0r[i] = 0.f; h1r[i] = 0.f; c1r[i] = 0.f; }

  short8 wb3[3][8];
  float4 xn0, xn1, xn2, xn3;

  // prologue: L(0), X(0), L(1), L(2)  — matches steady-state issue order
  LOADPH(wb3[0], lane_voff + 0u * 8192u);
  {
    uint32_t vox = xvbase;   // t=0 always valid (len >= 1)
    GLX(xn0, vox, "0"); GLX(xn1, vox, "16"); GLX(xn2, vox, "128"); GLX(xn3, vox, "144");
  }
  LOADPH(wb3[1], lane_voff + 1u * 8192u);
  LOADPH(wb3[2], lane_voff + 2u * 8192u);

  for (int t = 0; t < maxlen; t++) {
    // ---- consume x (issued at prev phase 24 / prologue): queue = L,X,L,L ----
    WAITV("16");
    short8 xa0, xa1;
    {
      float xf[8];
      xf[0]=xn0.x; xf[1]=xn0.y; xf[2]=xn0.z; xf[3]=xn0.w;
      xf[4]=xn1.x; xf[5]=xn1.y; xf[6]=xn1.z; xf[7]=xn1.w;
      #pragma unroll
      for (int i = 0; i < 8; i++) xa0[i] = (short)f2bf(xf[i]);
      xf[0]=xn2.x; xf[1]=xn2.y; xf[2]=xn2.z; xf[3]=xn2.w;
      xf[4]=xn3.x; xf[5]=xn3.y; xf[6]=xn3.z; xf[7]=xn3.w;
      #pragma unroll
      for (int i = 0; i < 8; i++) xa1[i] = (short)f2bf(xf[i]);
    }

    short8 ah0[8];
    #pragma unroll
    for (int kf = 0; kf < 8; kf++)
      ah0[kf] = *(const short8*)&h0p[lr][kf * 32 + lg * 8];
    BLOCK_BARRIER();   // A: h-plane reads done before any writes this step

    f32x4 acc0[8];
    #pragma unroll
    for (int nt = 0; nt < 8; nt++) acc0[nt] = (f32x4){0.f, 0.f, 0.f, 0.f};

    // phases 0-1: wih0
    #pragma unroll
    for (int p = 0; p < 2; p++) {
      short8* bp = wb3[p];           // p%3 == p here
      if (p == 0) { WAITV("20"); } else { WAITV("16"); }
      short8 rf[8];
      #pragma unroll
      for (int f = 0; f < 8; f++) rf[f] = bp[f];
      LOADPH(bp, lane_voff + (uint32_t)(p + 3) * 8192u);
      #pragma unroll
      for (int f = 0; f < 8; f++) {
        int nt = p * 4 + (f >> 1);
        acc0[nt] = __builtin_amdgcn_mfma_f32_16x16x32_bf16((f & 1) ? xa1 : xa0, rf[f], acc0[nt], 0, 0, 0);
      }
    }
    // phases 2-9: whh0
    #pragma unroll
    for (int p = 2; p < 10; p++) {
      short8* bp = wb3[p % 3];
      WAITV("16");
      short8 rf[8];
      #pragma unroll
      for (int f = 0; f < 8; f++) rf[f] = bp[f];
      LOADPH(bp, lane_voff + (uint32_t)(p + 3) * 8192u);
      #pragma unroll
      for (int f = 0; f < 8; f++)
        acc0[p - 2] = __builtin_amdgcn_mfma_f32_16x16x32_bf16(ah0[f], rf[f], acc0[p - 2], 0, 0, 0);
    }

    // cell 0 -> write h0 plane; read h1 before barrier B (writes to h1p are post-B)
    #pragma unroll
    for (int h2 = 0; h2 < 2; h2++) {
      #pragma unroll
      for (int v = 0; v < 4; v++) {
        float gi = acc0[h2 * 4 + 0][v] + b0r[h2 * 4 + 0];
        float gf = acc0[h2 * 4 + 1][v] + b0r[h2 * 4 + 1];
        float gg = acc0[h2 * 4 + 2][v] + b0r[h2 * 4 + 2];
        float go = acc0[h2 * 4 + 3][v] + b0r[h2 * 4 + 3];
        float ii = sigm(gi), ff = sigm(gf), gv = tanhf_(gg), oo = sigm(go);
        float cn = ff * c0r[h2 * 4 + v] + ii * gv;
        float hn = oo * tanhf_(cn);
        if (t < len_r[v]) { c0r[h2 * 4 + v] = cn; h0r[h2 * 4 + v] = hn; }
        h0p[lg * 4 + v][w * 32 + h2 * 16 + lr] = f2bf(h0r[h2 * 4 + v]);
      }
    }
    short8 ah1[8];
    #pragma unroll
    for (int kf = 0; kf < 8; kf++)
      ah1[kf] = *(const short8*)&h1p[lr][kf * 32 + lg * 8];
    BLOCK_BARRIER();   // B: h0 plane (y0) visible; h1 reads done

    short8 ay[8];
    #pragma unroll
    for (int kf = 0; kf < 8; kf++)
      ay[kf] = *(const short8*)&h0p[lr][kf * 32 + lg * 8];

    f32x4 acc1[8];
    #pragma unroll
    for (int nt = 0; nt < 8; nt++) acc1[nt] = (f32x4){0.f, 0.f, 0.f, 0.f};

    // phases 10-17: wih1 (A = y0)
    #pragma unroll
    for (int p = 10; p < 18; p++) {
      short8* bp = wb3[p % 3];
      WAITV("16");
      short8 rf[8];
      #pragma unroll
      for (int f = 0; f < 8; f++) rf[f] = bp[f];
      LOADPH(bp, lane_voff + (uint32_t)(p + 3) * 8192u);
      #pragma unroll
      for (int f = 0; f < 8; f++)
        acc1[p - 10] = __builtin_amdgcn_mfma_f32_16x16x32_bf16(ay[f], rf[f], acc1[p - 10], 0, 0, 0);
    }
    // phases 18-25: whh1 (A = h1 prev); phase 24 also issues next-step x
    #pragma unroll
    for (int p = 18; p < 26; p++) {
      short8* bp = wb3[p % 3];
      if (p >= 25) { WAITV("20"); } else { WAITV("16"); }
      short8 rf[8];
      #pragma unroll
      for (int f = 0; f < 8; f++) rf[f] = bp[f];
      LOADPH(bp, lane_voff + (uint32_t)((p + 3) % 27) * 8192u);
      if (p == 24) {
        int tn = t + 1;
        int tt = (tn < lenrow) ? tn : 0;
        uint32_t vox = xvbase + (uint32_t)tt * 256u;
        GLX(xn0, vox, "0"); GLX(xn1, vox, "16"); GLX(xn2, vox, "128"); GLX(xn3, vox, "144");
      }
      #pragma unroll
      for (int f = 0; f < 8; f++)
        acc1[p - 18] = __builtin_amdgcn_mfma_f32_16x16x32_bf16(ah1[f], rf[f], acc1[p - 18], 0, 0, 0);
    }

    // cell 1 -> write h1 plane
    #pragma unroll
    for (int h2 = 0; h2 < 2; h2++) {
      #pragma unroll
      for (int v = 0; v < 4; v++) {
        float gi = acc1[h2 * 4 + 0][v] + b1r[h2 * 4 + 0];
        float gf = acc1[h2 * 4 + 1][v] + b1r[h2 * 4 + 1];
        float gg = acc1[h2 * 4 + 2][v] + b1r[h2 * 4 + 2];
        float go = acc1[h2 * 4 + 3][v] + b1r[h2 * 4 + 3];
        float ii = sigm(gi), ff = sigm(gf), gv = tanhf_(gg), oo = sigm(go);
        float cn = ff * c1r[h2 * 4 + v] + ii * gv;
        float hn = oo * tanhf_(cn);
        if (t < len_r[v]) { c1r[h2 * 4 + v] = cn; h1r[h2 * 4 + v] = hn; }
        h1p[lg * 4 + v][w * 32 + h2 * 16 + lr] = f2bf(h1r[h2 * 4 + v]);
      }
    }
    BLOCK_BARRIER();   // C: h1 plane (y1) visible

    // phase 26: wfc (A = y1) — all waves wait+issue (uniform vmcnt protocol)
    {
      short8* bp = wb3[2];          // 26 % 3 == 2
      WAITV("20");
      short8 rf[8];
      #pragma unroll
      for (int f = 0; f < 8; f++) rf[f] = bp[f];
      LOADPH(bp, lane_voff + 2u * 8192u);   // next step's phase 2
      if (w < 2) {
        short8 ay1[8];
        #pragma unroll
        for (int f = 0; f < 8; f++)
          ay1[f] = *(const short8*)&h1p[lr][f * 32 + lg * 8];
        f32x4 a = {0.f, 0.f, 0.f, 0.f};
        #pragma unroll
        for (int f = 0; f < 8; f++)
          a = __builtin_amdgcn_mfma_f32_16x16x32_bf16(ay1[f], rf[f], a, 0, 0, 0);
        #pragma unroll
        for (int v = 0; v < 4; v++) {
          float val = a[v] + bfc_r;
          const float* p_ = &out[obase[v] + (long long)t * O_];
          if (t < len_r[v]) GSTORE(p_, val);
        }
      }
    }
  }

  asm volatile("s_waitcnt vmcnt(0) lgkmcnt(0)" ::: "memory");
  SBAR0;

  // final states
  #pragma unroll
  for (int h2 = 0; h2 < 2; h2++) {
    #pragma unroll
    for (int v = 0; v < 4; v++) {
      int r = lg * 4 + v;
      long long sg = (long long)g * MBLK + r;
      int j = w * 32 + h2 * 16 + lr;
      __builtin_nontemporal_store(h0r[h2 * 4 + v], &out[HOFF + sg * H_ + j]);
      __builtin_nontemporal_store(h1r[h2 * 4 + v], &out[HOFF + 524288 + sg * H_ + j]);
      __builtin_nontemporal_store(c0r[h2 * 4 + v], &out[COFF + sg * H_ + j]);
      __builtin_nontemporal_store(c1r[h2 * 4 + v], &out[COFF + 524288 + sg * H_ + j]);
    }
  }
}

extern "C" void kernel_launch(void* const* d_in, const int* in_sizes, int n_in,
                              void* d_out, int out_size, void* d_ws, size_t ws_size,
                              hipStream_t stream) {
  const float* x    = (const float*)d_in[0];
  const int*   lpp  = (const int*)d_in[2];
  const float* Wih0 = (const float*)d_in[4];
  const float* Whh0 = (const float*)d_in[5];
  const float* bih0 = (const float*)d_in[6];
  const float* bhh0 = (const float*)d_in[7];
  const float* Wih1 = (const float*)d_in[8];
  const float* Whh1 = (const float*)d_in[9];
  const float* bih1 = (const float*)d_in[10];
  const float* bhh1 = (const float*)d_in[11];
  const float* Wfc  = (const float*)d_in[12];
  const float* bfc  = (const float*)d_in[13];
  uint8_t* ws = (uint8_t*)d_ws;
  float* out = (float*)d_out;

  (void)hipMemsetAsync(d_out, 0, 8388608ull * 4, stream);

  k_starts<<<1, 16, 0, stream>>>(lpp, (int*)(ws + WS_STARTS));
  k_pack_stream<<<(8 * 27 * 4096 + 255) / 256, 256, 0, stream>>>(
      Wih0, Whh0, Wih1, Whh1, Wfc, (u16*)(ws + WS_STREAM));
  k_bias<<<4, 256, 0, stream>>>(bih0, bhh0, bih1, bhh1,
                                (float*)(ws + WS_B0), (float*)(ws + WS_B1));
  lstm_main<<<NBLOCKS, NTHREADS, 0, stream>>>(x, lpp, bfc, ws, out);
}

// Round 9
// 2751.765 us; speedup vs baseline: 1.5876x; 1.5876x over previous
//
#include <hip/hip_runtime.h>
#include <cstdint>

typedef unsigned short u16;
typedef __attribute__((ext_vector_type(8))) short short8;
typedef __attribute__((ext_vector_type(4))) float f32x4;
typedef __attribute__((ext_vector_type(4))) int i32x4;

#define B_ 16
#define P_ 128
#define T_ 16384
#define H_ 256
#define O_ 32
#define MBLK 16
#define NBLOCKS 128

#define HOFF 8388608LL
#define COFF 9437184LL

// ---------------- workspace layout ----------------
// shared small region
#define WS_STARTS 0
#define WS_B0     8192
#define WS_B1     12288
// new path
#define WS_WFC    16384      // 2 tiles x 8 kf x 1KB = 16 KB
#define WS_WIH0   32768      // wv*16KB + p*8KB + f*1KB   (128 KB)
#define WS_WHH0   163840     // wv*64KB + nt*8KB + kf*1KB (512 KB)
#define WS_WIH1   675840     // same layout (512 KB)
#define WS_WHH1   1187840    // (512 KB)
#define Y0F_OFF   4194304ULL               // [g][136 t][8 kf][1KB] = 142,606,336
#define XP1_OFF   150994944ULL             // [g][136 t][8 w][4 np][1KB] = 570,425,344
#define WS_NEED   (XP1_OFF + 128ULL*136ULL*32768ULL)   // 721,420,288
// R5 fallback stream
#define WS_STREAM 16384

#define SBAR0 __builtin_amdgcn_sched_barrier(0)
#define LGKM0 asm volatile("s_waitcnt lgkmcnt(0)" ::: "memory")
#define BLOCK_BARRIER() do { SBAR0; LGKM0; __builtin_amdgcn_s_barrier(); SBAR0; } while (0)
#define WAITV(NSTR) do { \
  asm volatile("s_waitcnt vmcnt(" NSTR ")" ::: "memory"); SBAR0; } while (0)

// loads straight to VGPRs, invisible to compiler vmcnt tracking (NO nt — R8 regression)
#define GL(dst, vo, IMMSTR) \
  asm volatile("global_load_dwordx4 %0, %1, %2 offset:" IMMSTR \
               : "=v"(dst) : "v"(vo), "s"(wbv))
#define LOADPH(bq, voff) do { \
  uint32_t vo_ = (voff); uint32_t vo2_ = vo_ + 4096u; \
  GL(bq[0], vo_,  "0");    GL(bq[1], vo_,  "1024"); \
  GL(bq[2], vo_,  "2048"); GL(bq[3], vo_,  "3072"); \
  GL(bq[4], vo2_, "0");    GL(bq[5], vo2_, "1024"); \
  GL(bq[6], vo2_, "2048"); GL(bq[7], vo2_, "3072"); } while (0)
#define LOADPH4(bq, voff) do { \
  uint32_t vo_ = (voff); \
  GL(bq[0], vo_, "0");    GL(bq[1], vo_, "1024"); \
  GL(bq[2], vo_, "2048"); GL(bq[3], vo_, "3072"); } while (0)

#define GLX(dst, vo, IMMSTR) \
  asm volatile("global_load_dwordx4 %0, %1, %2 offset:" IMMSTR \
               : "=v"(dst) : "v"(vo), "s"(xbv))
#define GSTORE(ptr, val) \
  asm volatile("global_store_dword %0, %1, off" :: "v"(ptr), "v"(val))
#define GSTORE4(ptr, val) \
  asm volatile("global_store_dwordx4 %0, %1, off" :: "v"(ptr), "v"(val))

__device__ __forceinline__ u16 f2bf(float f) {
  uint32_t u = __float_as_uint(f);
  u += 0x7FFFu + ((u >> 16) & 1u);
  return (u16)(u >> 16);
}
__device__ __forceinline__ float bf2f(u16 b) {
  return __uint_as_float(((uint32_t)b) << 16);
}
__device__ __forceinline__ float sigm(float x) { return 1.f / (1.f + __expf(-x)); }
__device__ __forceinline__ float tanhf_(float x) {
  float e = __expf(-2.f * fabsf(x));
  float t = (1.f - e) / (1.f + e);
  return x < 0.f ? -t : t;
}

__global__ void k_starts(const int* __restrict__ lpp, int* __restrict__ starts) {
  int b = threadIdx.x;
  if (b >= B_) return;
  int run = 0;
  for (int p = 0; p < P_; p++) { starts[b * P_ + p] = run; run += lpp[b * P_ + p]; }
}

// permuted bias (same as R5)
__global__ void k_bias(const float* bih0, const float* bhh0,
                       const float* bih1, const float* bhh1,
                       float* b0, float* b1) {
  int n = blockIdx.x * 256 + threadIdx.x;
  if (n >= 1024) return;
  int wv = n >> 7, r = n & 127, nt = r >> 4, c = n & 15;
  int row = (nt & 3) * 256 + wv * 32 + ((nt >> 2) << 4) + c;
  b0[n] = bih0[row] + bhh0[row];
  b1[n] = bih1[row] + bhh1[row];
}

// generic weight packer: out[(((wv*8+nt)*KF + kf)*512 + lane*8 + i)]
// = W[permrow(wv,nt,c)][kf*32 + kg*8 + i]
__global__ void k_packW(const float* __restrict__ W, u16* __restrict__ o,
                        int K, int KF) {
  int idx = blockIdx.x * 256 + threadIdx.x;
  if (idx >= 8 * 8 * KF * 512) return;
  int i = idx & 7;
  int lane = (idx >> 3) & 63;
  int q = idx >> 9;
  int kf = q % KF;
  int r = q / KF;
  int nt = r & 7, wv = r >> 3;
  int c = lane & 15, kg = lane >> 4;
  int row = (nt & 3) * 256 + wv * 32 + ((nt >> 2) << 4) + c;
  o[idx] = f2bf(W[(long long)row * K + kf * 32 + kg * 8 + i]);
}

// wfc pack: out[(t*8+kf)*512 + lane*8 + i] = Wfc[t*16+c][kf*32+kg*8+i], t=0,1
__global__ void k_pack_wfc(const float* __restrict__ Wfc, u16* __restrict__ o) {
  int idx = blockIdx.x * 256 + threadIdx.x;
  if (idx >= 2 * 8 * 512) return;
  int i = idx & 7;
  int lane = (idx >> 3) & 63;
  int q = idx >> 9;
  int kf = q & 7, t = q >> 3;
  int c = lane & 15, kg = lane >> 4;
  o[idx] = f2bf(Wfc[(t * 16 + c) * 256 + kf * 32 + kg * 8 + i]);
}

// =================== rec0: layer-0 recurrence ===================
// 10-phase ring-2 per step: p0-1 wih0 (8 ld), p2-9 whh0 (8 ld); x GLX(4) after p7.
// vmcnt ledger (steady): top wait 8 (retires x+p0); p1..p7 wait 8; p8,p9 wait 12.
__launch_bounds__(512, 1)
__global__ void rec0_k(const float* __restrict__ x,
                       const int* __restrict__ lpp,
                       const uint8_t* __restrict__ ws,
                       float* __restrict__ out) {
  const int g = blockIdx.x;
  const int tid = threadIdx.x;
  const int w = tid >> 6;
  const int lane = tid & 63;
  const int lr = lane & 15;
  const int lg = lane >> 4;

  __shared__ __align__(16) u16 h0p[16][264];
  __shared__ int len_s[16];
  __shared__ int start_s[16];
  __shared__ int bb_s[16];

  const int* starts = (const int*)(ws + WS_STARTS);
  if (tid < 16) {
    int sg = g * MBLK + tid;
    len_s[tid] = lpp[sg];
    start_s[tid] = starts[sg];
    bb_s[tid] = sg >> 7;
  }
  for (int i = tid; i < 16 * 264; i += 512) ((u16*)h0p)[i] = 0;
  __syncthreads();

  int maxlen = 0;
  #pragma unroll
  for (int i = 0; i < 16; i++) maxlen = max(maxlen, len_s[i]);
  int len_r[4];
  #pragma unroll
  for (int v = 0; v < 4; v++) len_r[v] = len_s[lg * 4 + v];

  const float* b0p = (const float*)(ws + WS_B0);
  float b0r[8];
  #pragma unroll
  for (int nt = 0; nt < 8; nt++) b0r[nt] = b0p[w * 128 + nt * 16 + lr];

  const unsigned long long wbv = (unsigned long long)ws;
  const unsigned long long xbv = (unsigned long long)x;
  const uint32_t lane16 = (uint32_t)lane * 16u;
  const uint32_t WIH0B = (uint32_t)WS_WIH0 + (uint32_t)w * 16384u + lane16;
  const uint32_t WHH0B = (uint32_t)WS_WHH0 + (uint32_t)w * 65536u + lane16;
  const int lenrow = len_s[lr];
  const uint32_t xvbase =
      ((uint32_t)bb_s[lr] * (uint32_t)T_ + (uint32_t)start_s[lr]) * 256u + (uint32_t)lg * 32u;
  // y0f write pointer (64-bit addr store)
  const uint8_t* y0f_base = ws + Y0F_OFF + (unsigned long long)g * (136ULL * 8192ULL)
                            + (uint32_t)w * 1024u + lane16;

  float h0r[8], c0r[8];
  #pragma unroll
  for (int i = 0; i < 8; i++) { h0r[i] = 0.f; c0r[i] = 0.f; }

  asm volatile("s_waitcnt vmcnt(0) lgkmcnt(0)" ::: "memory");
  SBAR0;

  short8 sA[8], sB[8];
  float4 xn0, xn1, xn2, xn3;

  // prologue: X(0), p0, p1
  {
    uint32_t vox = xvbase;
    GLX(xn0, vox, "0"); GLX(xn1, vox, "16"); GLX(xn2, vox, "128"); GLX(xn3, vox, "144");
  }
  LOADPH(sA, WIH0B + 0u);
  LOADPH(sB, WIH0B + 8192u);

  for (int t = 0; t < maxlen; t++) {
    WAITV("8");                 // retires x(t) + p0
    short8 xa0, xa1;
    {
      float xf[8];
      xf[0]=xn0.x; xf[1]=xn0.y; xf[2]=xn0.z; xf[3]=xn0.w;
      xf[4]=xn1.x; xf[5]=xn1.y; xf[6]=xn1.z; xf[7]=xn1.w;
      #pragma unroll
      for (int i = 0; i < 8; i++) xa0[i] = (short)f2bf(xf[i]);
      xf[0]=xn2.x; xf[1]=xn2.y; xf[2]=xn2.z; xf[3]=xn2.w;
      xf[4]=xn3.x; xf[5]=xn3.y; xf[6]=xn3.z; xf[7]=xn3.w;
      #pragma unroll
      for (int i = 0; i < 8; i++) xa1[i] = (short)f2bf(xf[i]);
    }
    short8 ahf[8];
    #pragma unroll
    for (int kf = 0; kf < 8; kf++)
      ahf[kf] = *(const short8*)&h0p[lr][kf * 32 + lg * 8];
    BLOCK_BARRIER();            // A: reads of h done before writes

    f32x4 acc[8];
    #pragma unroll
    for (int nt = 0; nt < 8; nt++) acc[nt] = (f32x4){0.f, 0.f, 0.f, 0.f};

    // p0: wih0a (already retired by top wait)
    {
      short8 rf[8];
      #pragma unroll
      for (int f = 0; f < 8; f++) rf[f] = sA[f];
      LOADPH(sA, WHH0B + 0u);                 // p2 = whh nt0
      #pragma unroll
      for (int f = 0; f < 8; f++)
        acc[f >> 1] = __builtin_amdgcn_mfma_f32_16x16x32_bf16((f & 1) ? xa1 : xa0, rf[f], acc[f >> 1], 0, 0, 0);
    }
    // p1: wih0b
    {
      WAITV("8");
      short8 rf[8];
      #pragma unroll
      for (int f = 0; f < 8; f++) rf[f] = sB[f];
      LOADPH(sB, WHH0B + 8192u);              // p3 = whh nt1
      #pragma unroll
      for (int f = 0; f < 8; f++)
        acc[4 + (f >> 1)] = __builtin_amdgcn_mfma_f32_16x16x32_bf16((f & 1) ? xa1 : xa0, rf[f], acc[4 + (f >> 1)], 0, 0, 0);
    }
    // p2..p9: whh0 nt=p-2
    #pragma unroll
    for (int p = 2; p < 10; p++) {
      short8* sl = (p & 1) ? sB : sA;
      if (p >= 8) { WAITV("12"); } else { WAITV("8"); }
      short8 rf[8];
      #pragma unroll
      for (int f = 0; f < 8; f++) rf[f] = sl[f];
      if (p <= 7)      LOADPH(sl, WHH0B + (uint32_t)p * 8192u);   // p+2 -> nt=p
      else if (p == 8) LOADPH(sl, WIH0B + 0u);                    // p0'
      else             LOADPH(sl, WIH0B + 8192u);                 // p1'
      if (p == 7) {
        int tn = t + 1;
        int tt = (tn < lenrow) ? tn : 0;
        uint32_t vox = xvbase + (uint32_t)tt * 256u;
        GLX(xn0, vox, "0"); GLX(xn1, vox, "16"); GLX(xn2, vox, "128"); GLX(xn3, vox, "144");
      }
      #pragma unroll
      for (int f = 0; f < 8; f++)
        acc[p - 2] = __builtin_amdgcn_mfma_f32_16x16x32_bf16(ahf[f], rf[f], acc[p - 2], 0, 0, 0);
    }

    // cell 0
    #pragma unroll
    for (int h2 = 0; h2 < 2; h2++) {
      #pragma unroll
      for (int v = 0; v < 4; v++) {
        float gi = acc[h2 * 4 + 0][v] + b0r[h2 * 4 + 0];
        float gf = acc[h2 * 4 + 1][v] + b0r[h2 * 4 + 1];
        float gg = acc[h2 * 4 + 2][v] + b0r[h2 * 4 + 2];
        float go = acc[h2 * 4 + 3][v] + b0r[h2 * 4 + 3];
        float ii = sigm(gi), ff = sigm(gf), gv = tanhf_(gg), oo = sigm(go);
        float cn = ff * c0r[h2 * 4 + v] + ii * gv;
        float hn = oo * tanhf_(cn);
        if (t < len_r[v]) { c0r[h2 * 4 + v] = cn; h0r[h2 * 4 + v] = hn; }
        h0p[lg * 4 + v][w * 32 + h2 * 16 + lr] = f2bf(h0r[h2 * 4 + v]);
      }
    }
    BLOCK_BARRIER();            // B: new h visible
    // y0f store: wave w stores frag kf=w of the new h plane
    {
      short8 yf = *(const short8*)&h0p[lr][w * 32 + lg * 8];
      const uint8_t* p_ = y0f_base + (uint32_t)t * 8192u;
      GSTORE4(p_, *(const i32x4*)&yf);
    }
  }

  asm volatile("s_waitcnt vmcnt(0) lgkmcnt(0)" ::: "memory");
  SBAR0;
  #pragma unroll
  for (int h2 = 0; h2 < 2; h2++) {
    #pragma unroll
    for (int v = 0; v < 4; v++) {
      int r = lg * 4 + v;
      long long sg = (long long)g * MBLK + r;
      int j = w * 32 + h2 * 16 + lr;
      __builtin_nontemporal_store(h0r[h2 * 4 + v], &out[HOFF + sg * H_ + j]);
      __builtin_nontemporal_store(c0r[h2 * 4 + v], &out[COFF + sg * H_ + j]);
    }
  }
}

// =================== gemm1: xp1 = y0 @ Wih1^T + b1 ===================
// xp1[g][t][w][np][lane*16]: short8 elem (2v+j) = col nt=np*2+j, seq v  (bf16)
__launch_bounds__(512, 1)
__global__ void gemm1_k(const uint8_t* __restrict__ ws_c, uint8_t* __restrict__ ws) {
  const int g = blockIdx.x;
  const int tid = threadIdx.x;
  const int w = tid >> 6;
  const int lane = tid & 63;
  const int lr = lane & 15;

  __shared__ __align__(16) u16 y0s[8][8][512];   // [tt][kf][1KB]

  const float* b1p = (const float*)(ws_c + WS_B1);
  float b1r[8];
  #pragma unroll
  for (int nt = 0; nt < 8; nt++) b1r[nt] = b1p[w * 128 + nt * 16 + lr];

  const uint8_t* y0f = ws_c + Y0F_OFF + (unsigned long long)g * (136ULL * 8192ULL);
  const u16* wih1 = (const u16*)(ws_c + WS_WIH1) + (size_t)w * 32768 + lane * 8; // u16 units
  uint8_t* xp1 = ws + XP1_OFF + (unsigned long long)g * (136ULL * 32768ULL)
               + (uint32_t)w * 4096u + (uint32_t)lane * 16u;

  for (int c = 0; c < 17; c++) {
    const int t0 = c * 8;
    // stage 64 KB of y0f
    #pragma unroll
    for (int r = 0; r < 2; r++) {
      int off = (tid + r * 512) * 16;
      *(i32x4*)((uint8_t*)y0s + off) = *(const i32x4*)(y0f + (size_t)t0 * 8192 + off);
    }
    __syncthreads();
    #pragma unroll
    for (int np = 0; np < 4; np++) {
      f32x4 acc[8][2];
      #pragma unroll
      for (int tt = 0; tt < 8; tt++) {
        acc[tt][0] = (f32x4){0.f,0.f,0.f,0.f};
        acc[tt][1] = (f32x4){0.f,0.f,0.f,0.f};
      }
      #pragma unroll
      for (int kf = 0; kf < 8; kf++) {
        short8 bf0 = *(const short8*)(wih1 + (((np * 2 + 0) * 8 + kf) << 9));
        short8 bf1 = *(const short8*)(wih1 + (((np * 2 + 1) * 8 + kf) << 9));
        #pragma unroll
        for (int tt = 0; tt < 8; tt++) {
          short8 a = *(const short8*)&y0s[tt][kf][lane * 8];
          acc[tt][0] = __builtin_amdgcn_mfma_f32_16x16x32_bf16(a, bf0, acc[tt][0], 0, 0, 0);
          acc[tt][1] = __builtin_amdgcn_mfma_f32_16x16x32_bf16(a, bf1, acc[tt][1], 0, 0, 0);
        }
      }
      #pragma unroll
      for (int tt = 0; tt < 8; tt++) {
        uint32_t d[4];
        #pragma unroll
        for (int v = 0; v < 4; v++) {
          u16 lo = f2bf(acc[tt][0][v] + b1r[np * 2 + 0]);
          u16 hi = f2bf(acc[tt][1][v] + b1r[np * 2 + 1]);
          d[v] = (uint32_t)lo | ((uint32_t)hi << 16);
        }
        *(i32x4*)(xp1 + (size_t)(t0 + tt) * 32768 + np * 1024) = *(const i32x4*)d;
      }
    }
    __syncthreads();
  }
}

// =================== rec1: layer-1 recurrence + FC ===================
// 9-phase ring-3: p0 xp1 (4 ld), p1-8 whh1 (8 ld). waits [16 x7, 12, 12].
__launch_bounds__(512, 1)
__global__ void rec1_k(const int* __restrict__ lpp,
                       const float* __restrict__ bfc,
                       const uint8_t* __restrict__ ws,
                       float* __restrict__ out) {
  const int g = blockIdx.x;
  const int tid = threadIdx.x;
  const int w = tid >> 6;
  const int lane = tid & 63;
  const int lr = lane & 15;
  const int lg = lane >> 4;

  __shared__ __align__(16) u16 h1p[16][264];
  __shared__ int len_s[16];
  __shared__ int start_s[16];
  __shared__ int bb_s[16];

  const int* starts = (const int*)(ws + WS_STARTS);
  if (tid < 16) {
    int sg = g * MBLK + tid;
    len_s[tid] = lpp[sg];
    start_s[tid] = starts[sg];
    bb_s[tid] = sg >> 7;
  }
  for (int i = tid; i < 16 * 264; i += 512) ((u16*)h1p)[i] = 0;
  __syncthreads();

  int maxlen = 0;
  #pragma unroll
  for (int i = 0; i < 16; i++) maxlen = max(maxlen, len_s[i]);
  int len_r[4];
  long long obase[4];
  #pragma unroll
  for (int v = 0; v < 4; v++) {
    int r = lg * 4 + v;
    len_r[v] = len_s[r];
    obase[v] = ((long long)bb_s[r] * T_ + start_s[r]) * O_ + (w & 1) * 16 + lr;
  }
  float bfc_r = (w < 2) ? bfc[w * 16 + lr] : 0.f;

  const unsigned long long wbv = (unsigned long long)ws;
  const uint32_t lane16 = (uint32_t)lane * 16u;
  const uint32_t WHH1B = (uint32_t)WS_WHH1 + (uint32_t)w * 65536u + lane16;
  const uint32_t WFCB  = (uint32_t)WS_WFC + (uint32_t)((w < 2) ? w : 0) * 8192u + lane16;
  const uint32_t XP1B  = (uint32_t)XP1_OFF + (uint32_t)g * (136u * 32768u)
                       + (uint32_t)w * 4096u + lane16;   // + t*32768

  float h1r[8], c1r[8];
  #pragma unroll
  for (int i = 0; i < 8; i++) { h1r[i] = 0.f; c1r[i] = 0.f; }

  asm volatile("s_waitcnt vmcnt(0) lgkmcnt(0)" ::: "memory");
  SBAR0;

  // wfc preload (constant) then drain
  short8 wfcr[8];
  LOADPH(wfcr, WFCB);
  WAITV("0");

  short8 wb3[3][8];
  // prologue: p0 (xp1 t=0), p1 (whh nt0), p2 (whh nt1)
  LOADPH4(wb3[0], XP1B + 0u);
  LOADPH(wb3[1], WHH1B + 0u);
  LOADPH(wb3[2], WHH1B + 8192u);

  for (int t = 0; t < maxlen; t++) {
    f32x4 acc[8];
    // p0: xp1 -> acc init (bias already folded in by gemm1)
    {
      WAITV("16");
      #pragma unroll
      for (int np = 0; np < 4; np++) {
        short8 s = wb3[0][np];
        #pragma unroll
        for (int j = 0; j < 2; j++) {
          f32x4 a;
          #pragma unroll
          for (int v = 0; v < 4; v++) a[v] = bf2f((u16)s[v * 2 + j]);
          acc[np * 2 + j] = a;
        }
      }
      LOADPH(wb3[0], WHH1B + 2u * 8192u);     // p3 = whh nt2
    }
    short8 ahf[8];
    #pragma unroll
    for (int kf = 0; kf < 8; kf++)
      ahf[kf] = *(const short8*)&h1p[lr][kf * 32 + lg * 8];
    BLOCK_BARRIER();            // A

    // p1..p8: whh1 nt=p-1
    #pragma unroll
    for (int p = 1; p < 9; p++) {
      short8* sl = wb3[p % 3];
      if (p >= 7) { WAITV("12"); } else { WAITV("16"); }
      short8 rf[8];
      #pragma unroll
      for (int f = 0; f < 8; f++) rf[f] = sl[f];
      if (p <= 5)      LOADPH(sl, WHH1B + (uint32_t)(p + 2) * 8192u);  // p+3 -> nt=p+2
      else if (p == 6) { LOADPH4(sl, XP1B + (uint32_t)(t + 1) * 32768u); } // p0'(t+1)
      else if (p == 7) LOADPH(sl, WHH1B + 0u);                          // p1'
      else             LOADPH(sl, WHH1B + 8192u);                       // p2'
      #pragma unroll
      for (int f = 0; f < 8; f++)
        acc[p - 1] = __builtin_amdgcn_mfma_f32_16x16x32_bf16(ahf[f], rf[f], acc[p - 1], 0, 0, 0);
    }

    // cell 1 (no bias — folded into xp1)
    #pragma unroll
    for (int h2 = 0; h2 < 2; h2++) {
      #pragma unroll
      for (int v = 0; v < 4; v++) {
        float gi = acc[h2 * 4 + 0][v];
        float gf = acc[h2 * 4 + 1][v];
        float gg = acc[h2 * 4 + 2][v];
        float go = acc[h2 * 4 + 3][v];
        float ii = sigm(gi), ff = sigm(gf), gv = tanhf_(gg), oo = sigm(go);
        float cn = ff * c1r[h2 * 4 + v] + ii * gv;
        float hn = oo * tanhf_(cn);
        if (t < len_r[v]) { c1r[h2 * 4 + v] = cn; h1r[h2 * 4 + v] = hn; }
        h1p[lg * 4 + v][w * 32 + h2 * 16 + lr] = f2bf(h1r[h2 * 4 + v]);
      }
    }
    BLOCK_BARRIER();            // B

    // FC (waves 0,1)
    if (w < 2) {
      short8 ay1[8];
      #pragma unroll
      for (int f = 0; f < 8; f++)
        ay1[f] = *(const short8*)&h1p[lr][f * 32 + lg * 8];
      f32x4 a = {0.f, 0.f, 0.f, 0.f};
      #pragma unroll
      for (int f = 0; f < 8; f++)
        a = __builtin_amdgcn_mfma_f32_16x16x32_bf16(ay1[f], wfcr[f], a, 0, 0, 0);
      #pragma unroll
      for (int v = 0; v < 4; v++) {
        float val = a[v] + bfc_r;
        const float* p_ = &out[obase[v] + (long long)t * O_];
        if (t < len_r[v]) GSTORE(p_, val);
      }
    }
  }

  asm volatile("s_waitcnt vmcnt(0) lgkmcnt(0)" ::: "memory");
  SBAR0;
  #pragma unroll
  for (int h2 = 0; h2 < 2; h2++) {
    #pragma unroll
    for (int v = 0; v < 4; v++) {
      int r = lg * 4 + v;
      long long sg = (long long)g * MBLK + r;
      int j = w * 32 + h2 * 16 + lr;
      __builtin_nontemporal_store(h1r[h2 * 4 + v], &out[HOFF + 524288 + sg * H_ + j]);
      __builtin_nontemporal_store(c1r[h2 * 4 + v], &out[COFF + 524288 + sg * H_ + j]);
    }
  }
}

// =================== R5 fallback (verbatim passing version, no nt) ===================
__global__ void k_pack_stream_r5(const float* __restrict__ Wih0, const float* __restrict__ Whh0,
                                 const float* __restrict__ Wih1, const float* __restrict__ Whh1,
                                 const float* __restrict__ Wfc, u16* __restrict__ o) {
  int idx = blockIdx.x * 256 + threadIdx.x;
  if (idx >= 8 * 27 * 4096) return;
  int i = idx & 7;
  int lane = (idx >> 3) & 63;
  int f = (idx >> 9) & 7;
  int pp = idx >> 12;
  int p = pp % 27, wv = pp / 27;
  int c = lane & 15, kg = lane >> 4, k = kg * 8 + i;
  float val;
  if (p < 2)        { int nt = p * 4 + (f >> 1), kf = f & 1;
                      int row = (nt & 3) * 256 + wv * 32 + ((nt >> 2) << 4) + c;
                      val = Wih0[row * 64 + kf * 32 + k]; }
  else if (p < 10)  { int nt = p - 2;
                      int row = (nt & 3) * 256 + wv * 32 + ((nt >> 2) << 4) + c;
                      val = Whh0[row * 256 + f * 32 + k]; }
  else if (p < 18)  { int nt = p - 10;
                      int row = (nt & 3) * 256 + wv * 32 + ((nt >> 2) << 4) + c;
                      val = Wih1[row * 256 + f * 32 + k]; }
  else if (p < 26)  { int nt = p - 18;
                      int row = (nt & 3) * 256 + wv * 32 + ((nt >> 2) << 4) + c;
                      val = Whh1[row * 256 + f * 32 + k]; }
  else              { int tile = wv & 1; int row = tile * 16 + c;
                      val = Wfc[row * 256 + f * 32 + k]; }
  o[idx] = f2bf(val);
}

__launch_bounds__(512, 1)
__global__ void lstm_main_r5(const float* __restrict__ x,
                             const int* __restrict__ lpp,
                             const float* __restrict__ bfc,
                             const uint8_t* __restrict__ ws,
                             float* __restrict__ out) {
  const int g = blockIdx.x;
  const int tid = threadIdx.x;
  const int w = tid >> 6;
  const int lane = tid & 63;
  const int lr = lane & 15;
  const int lg = lane >> 4;

  __shared__ __align__(16) u16 h0p[16][264];
  __shared__ __align__(16) u16 h1p[16][264];
  __shared__ int len_s[16];
  __shared__ int start_s[16];
  __shared__ int bb_s[16];

  const int* starts = (const int*)(ws + WS_STARTS);
  if (tid < 16) {
    int sg = g * MBLK + tid;
    len_s[tid] = lpp[sg];
    start_s[tid] = starts[sg];
    bb_s[tid] = sg >> 7;
  }
  for (int i = tid; i < 16 * 264; i += 512) {
    ((u16*)h0p)[i] = 0;
    ((u16*)h1p)[i] = 0;
  }
  __syncthreads();

  int maxlen = 0;
  #pragma unroll
  for (int i = 0; i < 16; i++) maxlen = max(maxlen, len_s[i]);
  int len_r[4];
  long long obase[4];
  #pragma unroll
  for (int v = 0; v < 4; v++) {
    int r = lg * 4 + v;
    len_r[v] = len_s[r];
    obase[v] = ((long long)bb_s[r] * T_ + start_s[r]) * O_ + (w & 1) * 16 + lr;
  }

  const float* b0p = (const float*)(ws + WS_B0);
  const float* b1p = (const float*)(ws + WS_B1);
  float b0r[8], b1r[8];
  #pragma unroll
  for (int nt = 0; nt < 8; nt++) {
    b0r[nt] = b0p[w * 128 + nt * 16 + lr];
    b1r[nt] = b1p[w * 128 + nt * 16 + lr];
  }
  float bfc_r = (w < 2) ? bfc[w * 16 + lr] : 0.f;

  const unsigned long long wbv = (unsigned long long)(ws + WS_STREAM);
  const unsigned long long xbv = (unsigned long long)x;
  const uint32_t lane_voff = ((uint32_t)w * 27u * 4096u + (uint32_t)lane * 8u) * 2u;
  const int lenrow = len_s[lr];
  const uint32_t xvbase =
      ((uint32_t)bb_s[lr] * (uint32_t)T_ + (uint32_t)start_s[lr]) * 256u + (uint32_t)lg * 32u;

  float h0r[8], c0r[8], h1r[8], c1r[8];
  #pragma unroll
  for (int i = 0; i < 8; i++) { h0r[i] = 0.f; c0r[i] = 0.f; h1r[i] = 0.f; c1r[i] = 0.f; }

  short8 wb3[3][8];
  float4 xn0, xn1, xn2, xn3;

  LOADPH(wb3[0], lane_voff + 0u * 8192u);
  {
    uint32_t vox = xvbase;
    GLX(xn0, vox, "0"); GLX(xn1, vox, "16"); GLX(xn2, vox, "128"); GLX(xn3, vox, "144");
  }
  LOADPH(wb3[1], lane_voff + 1u * 8192u);
  LOADPH(wb3[2], lane_voff + 2u * 8192u);

  for (int t = 0; t < maxlen; t++) {
    WAITV("16");
    short8 xa0, xa1;
    {
      float xf[8];
      xf[0]=xn0.x; xf[1]=xn0.y; xf[2]=xn0.z; xf[3]=xn0.w;
      xf[4]=xn1.x; xf[5]=xn1.y; xf[6]=xn1.z; xf[7]=xn1.w;
      #pragma unroll
      for (int i = 0; i < 8; i++) xa0[i] = (short)f2bf(xf[i]);
      xf[0]=xn2.x; xf[1]=xn2.y; xf[2]=xn2.z; xf[3]=xn2.w;
      xf[4]=xn3.x; xf[5]=xn3.y; xf[6]=xn3.z; xf[7]=xn3.w;
      #pragma unroll
      for (int i = 0; i < 8; i++) xa1[i] = (short)f2bf(xf[i]);
    }

    short8 ah0[8];
    #pragma unroll
    for (int kf = 0; kf < 8; kf++)
      ah0[kf] = *(const short8*)&h0p[lr][kf * 32 + lg * 8];
    BLOCK_BARRIER();

    f32x4 acc0[8];
    #pragma unroll
    for (int nt = 0; nt < 8; nt++) acc0[nt] = (f32x4){0.f, 0.f, 0.f, 0.f};

    #pragma unroll
    for (int p = 0; p < 2; p++) {
      short8* bp = wb3[p];
      if (p == 0) { WAITV("20"); } else { WAITV("16"); }
      short8 rf[8];
      #pragma unroll
      for (int f = 0; f < 8; f++) rf[f] = bp[f];
      LOADPH(bp, lane_voff + (uint32_t)(p + 3) * 8192u);
      #pragma unroll
      for (int f = 0; f < 8; f++) {
        int nt = p * 4 + (f >> 1);
        acc0[nt] = __builtin_amdgcn_mfma_f32_16x16x32_bf16((f & 1) ? xa1 : xa0, rf[f], acc0[nt], 0, 0, 0);
      }
    }
    #pragma unroll
    for (int p = 2; p < 10; p++) {
      short8* bp = wb3[p % 3];
      WAITV("16");
      short8 rf[8];
      #pragma unroll
      for (int f = 0; f < 8; f++) rf[f] = bp[f];
      LOADPH(bp, lane_voff + (uint32_t)(p + 3) * 8192u);
      #pragma unroll
      for (int f = 0; f < 8; f++)
        acc0[p - 2] = __builtin_amdgcn_mfma_f32_16x16x32_bf16(ah0[f], rf[f], acc0[p - 2], 0, 0, 0);
    }

    #pragma unroll
    for (int h2 = 0; h2 < 2; h2++) {
      #pragma unroll
      for (int v = 0; v < 4; v++) {
        float gi = acc0[h2 * 4 + 0][v] + b0r[h2 * 4 + 0];
        float gf = acc0[h2 * 4 + 1][v] + b0r[h2 * 4 + 1];
        float gg = acc0[h2 * 4 + 2][v] + b0r[h2 * 4 + 2];
        float go = acc0[h2 * 4 + 3][v] + b0r[h2 * 4 + 3];
        float ii = sigm(gi), ff = sigm(gf), gv = tanhf_(gg), oo = sigm(go);
        float cn = ff * c0r[h2 * 4 + v] + ii * gv;
        float hn = oo * tanhf_(cn);
        if (t < len_r[v]) { c0r[h2 * 4 + v] = cn; h0r[h2 * 4 + v] = hn; }
        h0p[lg * 4 + v][w * 32 + h2 * 16 + lr] = f2bf(h0r[h2 * 4 + v]);
      }
    }
    short8 ah1[8];
    #pragma unroll
    for (int kf = 0; kf < 8; kf++)
      ah1[kf] = *(const short8*)&h1p[lr][kf * 32 + lg * 8];
    BLOCK_BARRIER();

    short8 ay[8];
    #pragma unroll
    for (int kf = 0; kf < 8; kf++)
      ay[kf] = *(const short8*)&h0p[lr][kf * 32 + lg * 8];

    f32x4 acc1[8];
    #pragma unroll
    for (int nt = 0; nt < 8; nt++) acc1[nt] = (f32x4){0.f, 0.f, 0.f, 0.f};

    #pragma unroll
    for (int p = 10; p < 18; p++) {
      short8* bp = wb3[p % 3];
      WAITV("16");
      short8 rf[8];
      #pragma unroll
      for (int f = 0; f < 8; f++) rf[f] = bp[f];
      LOADPH(bp, lane_voff + (uint32_t)(p + 3) * 8192u);
      #pragma unroll
      for (int f = 0; f < 8; f++)
        acc1[p - 10] = __builtin_amdgcn_mfma_f32_16x16x32_bf16(ay[f], rf[f], acc1[p - 10], 0, 0, 0);
    }
    #pragma unroll
    for (int p = 18; p < 26; p++) {
      short8* bp = wb3[p % 3];
      if (p >= 25) { WAITV("20"); } else { WAITV("16"); }
      short8 rf[8];
      #pragma unroll
      for (int f = 0; f < 8; f++) rf[f] = bp[f];
      LOADPH(bp, lane_voff + (uint32_t)((p + 3) % 27) * 8192u);
      if (p == 24) {
        int tn = t + 1;
        int tt = (tn < lenrow) ? tn : 0;
        uint32_t vox = xvbase + (uint32_t)tt * 256u;
        GLX(xn0, vox, "0"); GLX(xn1, vox, "16"); GLX(xn2, vox, "128"); GLX(xn3, vox, "144");
      }
      #pragma unroll
      for (int f = 0; f < 8; f++)
        acc1[p - 18] = __builtin_amdgcn_mfma_f32_16x16x32_bf16(ah1[f], rf[f], acc1[p - 18], 0, 0, 0);
    }

    #pragma unroll
    for (int h2 = 0; h2 < 2; h2++) {
      #pragma unroll
      for (int v = 0; v < 4; v++) {
        float gi = acc1[h2 * 4 + 0][v] + b1r[h2 * 4 + 0];
        float gf = acc1[h2 * 4 + 1][v] + b1r[h2 * 4 + 1];
        float gg = acc1[h2 * 4 + 2][v] + b1r[h2 * 4 + 2];
        float go = acc1[h2 * 4 + 3][v] + b1r[h2 * 4 + 3];
        float ii = sigm(gi), ff = sigm(gf), gv = tanhf_(gg), oo = sigm(go);
        float cn = ff * c1r[h2 * 4 + v] + ii * gv;
        float hn = oo * tanhf_(cn);
        if (t < len_r[v]) { c1r[h2 * 4 + v] = cn; h1r[h2 * 4 + v] = hn; }
        h1p[lg * 4 + v][w * 32 + h2 * 16 + lr] = f2bf(h1r[h2 * 4 + v]);
      }
    }
    BLOCK_BARRIER();

    {
      short8* bp = wb3[2];
      WAITV("20");
      short8 rf[8];
      #pragma unroll
      for (int f = 0; f < 8; f++) rf[f] = bp[f];
      LOADPH(bp, lane_voff + 2u * 8192u);
      if (w < 2) {
        short8 ay1[8];
        #pragma unroll
        for (int f = 0; f < 8; f++)
          ay1[f] = *(const short8*)&h1p[lr][f * 32 + lg * 8];
        f32x4 a = {0.f, 0.f, 0.f, 0.f};
        #pragma unroll
        for (int f = 0; f < 8; f++)
          a = __builtin_amdgcn_mfma_f32_16x16x32_bf16(ay1[f], rf[f], a, 0, 0, 0);
        #pragma unroll
        for (int v = 0; v < 4; v++) {
          float val = a[v] + bfc_r;
          const float* p_ = &out[obase[v] + (long long)t * O_];
          if (t < len_r[v]) GSTORE(p_, val);
        }
      }
    }
  }

  asm volatile("s_waitcnt vmcnt(0) lgkmcnt(0)" ::: "memory");
  SBAR0;
  #pragma unroll
  for (int h2 = 0; h2 < 2; h2++) {
    #pragma unroll
    for (int v = 0; v < 4; v++) {
      int r = lg * 4 + v;
      long long sg = (long long)g * MBLK + r;
      int j = w * 32 + h2 * 16 + lr;
      __builtin_nontemporal_store(h0r[h2 * 4 + v], &out[HOFF + sg * H_ + j]);
      __builtin_nontemporal_store(h1r[h2 * 4 + v], &out[HOFF + 524288 + sg * H_ + j]);
      __builtin_nontemporal_store(c0r[h2 * 4 + v], &out[COFF + sg * H_ + j]);
      __builtin_nontemporal_store(c1r[h2 * 4 + v], &out[COFF + 524288 + sg * H_ + j]);
    }
  }
}

extern "C" void kernel_launch(void* const* d_in, const int* in_sizes, int n_in,
                              void* d_out, int out_size, void* d_ws, size_t ws_size,
                              hipStream_t stream) {
  const float* x    = (const float*)d_in[0];
  const int*   lpp  = (const int*)d_in[2];
  const float* Wih0 = (const float*)d_in[4];
  const float* Whh0 = (const float*)d_in[5];
  const float* bih0 = (const float*)d_in[6];
  const float* bhh0 = (const float*)d_in[7];
  const float* Wih1 = (const float*)d_in[8];
  const float* Whh1 = (const float*)d_in[9];
  const float* bih1 = (const float*)d_in[10];
  const float* bhh1 = (const float*)d_in[11];
  const float* Wfc  = (const float*)d_in[12];
  const float* bfc  = (const float*)d_in[13];
  uint8_t* ws = (uint8_t*)d_ws;
  float* out = (float*)d_out;

  (void)hipMemsetAsync(d_out, 0, 8388608ull * 4, stream);
  k_starts<<<1, 16, 0, stream>>>(lpp, (int*)(ws + WS_STARTS));
  k_bias<<<4, 256, 0, stream>>>(bih0, bhh0, bih1, bhh1,
                                (float*)(ws + WS_B0), (float*)(ws + WS_B1));

  if (ws_size >= WS_NEED) {
    // ---- new path: rec0 -> gemm1 -> rec1 ----
    k_packW<<<256, 256, 0, stream>>>(Wih0, (u16*)(ws + WS_WIH0), 64, 2);
    k_packW<<<1024, 256, 0, stream>>>(Whh0, (u16*)(ws + WS_WHH0), 256, 8);
    k_packW<<<1024, 256, 0, stream>>>(Wih1, (u16*)(ws + WS_WIH1), 256, 8);
    k_packW<<<1024, 256, 0, stream>>>(Whh1, (u16*)(ws + WS_WHH1), 256, 8);
    k_pack_wfc<<<32, 256, 0, stream>>>(Wfc, (u16*)(ws + WS_WFC));
    rec0_k<<<NBLOCKS, 512, 0, stream>>>(x, lpp, ws, out);
    gemm1_k<<<NBLOCKS, 512, 0, stream>>>(ws, ws);
    rec1_k<<<NBLOCKS, 512, 0, stream>>>(lpp, bfc, ws, out);
  } else {
    // ---- fallback: proven R5 single-kernel ----
    k_pack_stream_r5<<<(8 * 27 * 4096 + 255) / 256, 256, 0, stream>>>(
        Wih0, Whh0, Wih1, Whh1, Wfc, (u16*)(ws + WS_STREAM));
    lstm_main_r5<<<NBLOCKS, 512, 0, stream>>>(x, lpp, bfc, ws, out);
  }
}